// Round 1
// 1160.120 us; speedup vs baseline: 1.1047x; 1.1047x over previous
//
#include <hip/hip_runtime.h>
#include <cstdint>

#define DIVUP(a,b) (((a)+(b)-1)/(b))

typedef __attribute__((ext_vector_type(4))) float f32x4;
typedef __attribute__((ext_vector_type(8))) _Float16 half8;

// Direct global->LDS DMA, 16B per lane. LDS dest is WAVE-UNIFORM base + lane*16.
__device__ __forceinline__ void gload_lds16(const void* g, void* l) {
  __builtin_amdgcn_global_load_lds(
      (const __attribute__((address_space(1))) void*)g,
      (__attribute__((address_space(3))) void*)l, 16, 0, 0);
}

__device__ __forceinline__ float cubicw(float x) {
  // PyTorch bicubic kernel, a = -0.75
  float ax = fabsf(x);
  float ax2 = ax * ax;
  float ax3 = ax2 * ax;
  if (ax <= 1.0f) return 1.25f * ax3 - 2.25f * ax2 + 1.0f;
  if (ax < 2.0f)  return -0.75f * ax3 + 3.75f * ax2 - 6.0f * ax + 3.0f;
  return 0.0f;
}

// S[b,pix] = sum_c x[b,c,pix]^2
__global__ void sumsq_kernel(const float* __restrict__ x, float* __restrict__ S,
                             int C, int HW, int total) {
  int i = blockIdx.x * blockDim.x + threadIdx.x;
  if (i >= total) return;
  int pix = i % HW, b = i / HW;
  const float* p = x + (size_t)b * C * HW + pix;
  float s = 0.f;
  for (int c = 0; c < C; ++c) { float v = p[(size_t)c * HW]; s += v * v; }
  S[i] = s;
}

// invn[b,p] = 1 / max(sqrt(3x3 zero-padded window sum of S), 1e-12)
__global__ void invnorm_kernel(const float* __restrict__ S, float* __restrict__ invn,
                               int H, int W, int total) {
  int i = blockIdx.x * blockDim.x + threadIdx.x;
  if (i >= total) return;
  int p = i % (H * W), b = i / (H * W);
  int ph = p / W, pw = p % W;
  const float* Sb = S + (size_t)b * H * W;
  float s = 0.f;
  for (int ki = 0; ki < 3; ++ki) {
    int y = ph + ki - 1;
    if (y < 0 || y >= H) continue;
    for (int kj = 0; kj < 3; ++kj) {
      int xx = pw + kj - 1;
      if (xx < 0 || xx >= W) continue;
      s += Sb[y * W + xx];
    }
  }
  float n = fmaxf(sqrtf(s), 1e-12f);
  invn[i] = 1.0f / n;
}

// l-layout descriptors (fp32, D-major) for levels 1/2
__global__ void desc_l_kernel(const float* __restrict__ x, const float* __restrict__ invn,
                              float* __restrict__ out, int C, int H, int W, int total) {
  int i = blockIdx.x * blockDim.x + threadIdx.x;
  if (i >= total) return;
  int HW = H * W, D = C * 9;
  int p = i % HW;
  int d = (i / HW) % D;
  int b = i / (HW * D);
  int c = d / 9, r = d % 9, ki = r / 3, kj = r % 3;
  int ph = p / W, pw = p % W;
  int y = ph + ki - 1, xx = pw + kj - 1;
  float v = 0.f;
  if (y >= 0 && y < H && xx >= 0 && xx < W) v = x[((size_t)(b * C + c) * H + y) * W + xx];
  out[i] = v * invn[b * HW + p];
}

// r-layout descriptors (fp32, N-major) for levels 1/2
__global__ void desc_r_kernel(const float* __restrict__ x, const float* __restrict__ invn,
                              float* __restrict__ out, int C, int H, int W, int total) {
  int i = blockIdx.x * blockDim.x + threadIdx.x;
  if (i >= total) return;
  int HW = H * W, D = C * 9;
  int d = i % D;
  int p = (i / D) % HW;
  int b = i / (D * HW);
  int c = d / 9, r = d % 9, ki = r / 3, kj = r % 3;
  int ph = p / W, pw = p % W;
  int y = ph + ki - 1, xx = pw + kj - 1;
  float v = 0.f;
  if (y >= 0 && y < H && xx >= 0 && xx < W) v = x[((size_t)(b * C + c) * H + y) * W + xx];
  out[i] = v * invn[b * HW + p];
}

// Level-3 split-f16 descriptors, pixel-major [B][4096][576]:
// hi = f16(v), lo = f16((v-hi)*4096)  (scaled to stay f16-normal)
__global__ void desc_split_kernel(const float* __restrict__ x, const float* __restrict__ invn,
                                  _Float16* __restrict__ hi, _Float16* __restrict__ lo,
                                  int C, int H, int W, int total) {
  int i = blockIdx.x * blockDim.x + threadIdx.x;
  if (i >= total) return;
  int c = i % C;
  int p = (i / C) % (H * W);
  int b = i / (C * H * W);
  int ph = p / W, pw = p % W;
  float s = invn[b * H * W + p];
  size_t obase = ((size_t)b * H * W + p) * (size_t)(C * 9) + (size_t)c * 9;
  const float* xb = x + (size_t)(b * C + c) * H * W;
#pragma unroll
  for (int r = 0; r < 9; ++r) {
    int y = ph + r / 3 - 1, xx = pw + r % 3 - 1;
    float v = 0.f;
    if (y >= 0 && y < H && xx >= 0 && xx < W) v = xb[y * W + xx] * s;
    _Float16 h = (_Float16)v;
    float hf = (float)h;
    _Float16 l = (_Float16)((v - hf) * 4096.0f);
    hi[obase + r] = h;
    lo[obase + r] = l;
  }
}

// Axis-1 bicubic upsample to 4096 rows
__global__ void upsample_n_kernel(const float* __restrict__ Rin, float* __restrict__ out,
                                  int Nin, int cols, float invscale, int total) {
  int i = blockIdx.x * blockDim.x + threadIdx.x;
  if (i >= total) return;
  int j = i % cols;
  int n = (i / cols) & 4095;
  int b = i / (cols * 4096);
  float src = (n + 0.5f) * invscale - 0.5f;
  float f = floorf(src);
  float tt = src - f;
  int fi = (int)f;
  const float* Rb = Rin + (size_t)b * Nin * cols;
  float s = 0.f;
#pragma unroll
  for (int tp = 0; tp < 4; ++tp) {
    int ii = min(max(fi + tp - 1, 0), Nin - 1);
    s += cubicw(tt - (float)(tp - 1)) * Rb[(size_t)ii * cols + j];
  }
  out[i] = s;
}

__global__ void init_packed_kernel(unsigned long long* __restrict__ p, int n) {
  int i = blockIdx.x * blockDim.x + threadIdx.x;
  if (i < n) p[i] = 0ull;
}

// 64x64-tile fp32 GEMM (4x4 microtile), register-prefetch pipelined. R2/R1.
__global__ __launch_bounds__(256)
void gemm64_kernel(const float* __restrict__ A, const float* __restrict__ B,
                   float* __restrict__ C, int M, int N, int K) {
  int b = blockIdx.z;
  const float* Ab = A + (size_t)b * M * K;
  const float* Bb = B + (size_t)b * K * N;
  __shared__ float As[16][68];
  __shared__ float Bs[16][64];
  int row0 = blockIdx.y * 64;
  int col0 = blockIdx.x * 64;
  int t = threadIdx.x;
  int tx = t & 15, ty = t >> 4;
  float acc[4][4] = {};
  int la_r = t >> 2;
  int la_k = (t & 3) << 2;
  int lb_r = t >> 4;
  int lb_c = (t & 15) << 2;
  const float* Aptr = Ab + (size_t)(row0 + la_r) * K + la_k;
  const float* Bptr = Bb + (size_t)lb_r * N + col0 + lb_c;
  float4 av = *(const float4*)(Aptr);
  float4 bv = *(const float4*)(Bptr);
  for (int k0 = 0; k0 < K; k0 += 16) {
    __syncthreads();
    As[la_k + 0][la_r] = av.x;
    As[la_k + 1][la_r] = av.y;
    As[la_k + 2][la_r] = av.z;
    As[la_k + 3][la_r] = av.w;
    *(float4*)&Bs[lb_r][lb_c] = bv;
    __syncthreads();
    if (k0 + 16 < K) {
      av = *(const float4*)(Aptr + k0 + 16);
      bv = *(const float4*)(Bptr + (size_t)(k0 + 16) * N);
    }
#pragma unroll
    for (int k = 0; k < 16; ++k) {
      float4 a = *(const float4*)&As[k][ty << 2];
      float4 bq = *(const float4*)&Bs[k][tx << 2];
      float av4[4] = {a.x, a.y, a.z, a.w};
      float bv4[4] = {bq.x, bq.y, bq.z, bq.w};
#pragma unroll
      for (int ii = 0; ii < 4; ++ii)
#pragma unroll
        for (int jj = 0; jj < 4; ++jj)
          acc[ii][jj] = fmaf(av4[ii], bv4[jj], acc[ii][jj]);
    }
  }
  float* Cb = C + (size_t)b * M * N;
#pragma unroll
  for (int ii = 0; ii < 4; ++ii) {
    float4 v = make_float4(acc[ii][0], acc[ii][1], acc[ii][2], acc[ii][3]);
    *(float4*)&Cb[(size_t)(row0 + (ty << 2) + ii) * N + col0 + (tx << 2)] = v;
  }
}

// MFMA split-f16 GEMM, 128x128 workgroup tile, wave=64x64 (4x4 of 16x16x32),
// fused bicubic-tap add + /3 + packed max/argmax over the ref axis (rows).
//
// Round-N restructure:
//  - XCD-aware bijective blockIdx swizzle (2048 blocks, 8 XCDs): each XCD owns
//    8 contiguous row-panels -> A-panels (2.4MB) stay L2-resident instead of
//    being re-fetched from L3/HBM 32x (FETCH_SIZE was 182MB vs ~38MB unique).
//  - Staging via global_load_lds(16B): no register round-trip, no ds_write VALU.
//  - Double-buffered LDS (2 x 4 planes x 8KB = 64KB; free since VGPRs cap us at
//    2 blocks/CU anyway) with ONE __syncthreads per K-step: next tile's DMA
//    overlaps the full MFMA phase (~2Kcy > 900cy HBM latency).
//  - Both-sides 16B-chunk XOR swizzle (chunk3 ^= line&7, an involution) applied
//    to the per-lane global SOURCE address and the ds_read address; LDS dest
//    stays linear as global_load_lds requires (rule: both-sides-or-neither).
__global__ __launch_bounds__(256, 2)
void mfma_fused_kernel(const _Float16* __restrict__ Ahi, const _Float16* __restrict__ Alo,
                       const _Float16* __restrict__ Bhi, const _Float16* __restrict__ Blo,
                       const float* __restrict__ up2, const float* __restrict__ up1,
                       unsigned long long* __restrict__ packed) {
  const int K = 576;
  // ---- XCD swizzle: grid is (32,32,2) = 2048 blocks; 2048 % 8 == 0 -> bijective
  int bid = (blockIdx.z * 32 + blockIdx.y) * 32 + blockIdx.x;
  int swz = (bid & 7) * 256 + (bid >> 3);
  int bx = swz & 31;
  int by = (swz >> 5) & 31;
  int b  = swz >> 10;

  int row0 = by * 128;   // ref axis (n) — argmax axis
  int col0 = bx * 128;   // lr axis (m) — output positions
  int t = threadIdx.x;
  int lane = t & 63, wave = t >> 6;
  int wy = wave & 1, wx = wave >> 1;
  int quad = lane >> 4, lm = lane & 15;

  // LDS: [buf:2][plane:4][8KB tile]. plane 0=AH 1=AL 2=BH 3=BL.
  // Tile logical layout [128 rows][32 halves] (64B/row), stored with the
  // chunk swizzle: within each 128B line (2 rows, 8 x 16B chunks),
  // physical chunk = logical chunk3 ^ (line & 7).
  __shared__ _Float16 lds[2 * 4 * 4096];

  // ---- staging source offsets (per-lane, bytes into a [128][K] half-plane).
  // Linear dest chunk d = wave*128 + h*64 + lane; invert the swizzle to find
  // which (row, col16) of the tile must be fetched into that slot.
  int off[2];
#pragma unroll
  for (int h = 0; h < 2; ++h) {
    int d = wave * 128 + h * 64 + lane;
    int line = d >> 3;
    int c3 = (d & 7) ^ (line & 7);
    int row = (line << 1) | (c3 >> 2);
    int c = c3 & 3;
    off[h] = row * (K * 2) + c * 16;
  }
  const char* pg[4];
  pg[0] = (const char*)Ahi + ((size_t)b * 4096 + row0) * (size_t)K * 2;
  pg[1] = (const char*)Alo + ((size_t)b * 4096 + row0) * (size_t)K * 2;
  pg[2] = (const char*)Bhi + ((size_t)b * 4096 + col0) * (size_t)K * 2;
  pg[3] = (const char*)Blo + ((size_t)b * 4096 + col0) * (size_t)K * 2;

  // ---- fragment ds_read addresses (bytes into an 8KB plane), swizzled.
  // Frag (row, quad) reads 16B at logical row*64 + quad*16; per 8-lane service
  // group the swizzled slots are a permutation of 0..7 -> conflict-free.
  int ra[4], rb[4];
#pragma unroll
  for (int i = 0; i < 4; ++i) {
    int rowa = wy * 64 + i * 16 + lm;
    int la_ = rowa >> 1;
    ra[i] = la_ * 128 + (((((rowa & 1) << 2) | quad) ^ (la_ & 7)) << 4);
    int rowb = wx * 64 + i * 16 + lm;
    int lb_ = rowb >> 1;
    rb[i] = lb_ * 128 + (((((rowb & 1) << 2) | quad) ^ (lb_ & 7)) << 4);
  }

  f32x4 S1[4][4] = {};
  f32x4 S2[4][4] = {};

  // stage tile 0 into buf 0
#pragma unroll
  for (int p = 0; p < 4; ++p) {
    char* lb_ = (char*)lds + p * 8192 + wave * 2048;
    gload_lds16(pg[p] + off[0], lb_);
    gload_lds16(pg[p] + off[1], lb_ + 1024);
  }
  __syncthreads();

  int buf = 0;
  for (int t18 = 0; t18 < 18; ++t18) {
    const char* lb = (const char*)lds + buf * 32768;
    half8 aH[4], aL[4], bH[4], bL[4];
#pragma unroll
    for (int i = 0; i < 4; ++i) {
      aH[i] = *(const half8*)(lb + ra[i]);
      aL[i] = *(const half8*)(lb + 8192 + ra[i]);
      bH[i] = *(const half8*)(lb + 16384 + rb[i]);
      bL[i] = *(const half8*)(lb + 24576 + rb[i]);
    }
    // prefetch next tile into the other buffer; flies under the MFMA phase,
    // drained by the vmcnt(0) the compiler emits at the trailing barrier.
    if (t18 < 17) {
      int kbyte = (t18 + 1) * 64;
#pragma unroll
      for (int p = 0; p < 4; ++p) {
        char* lw = (char*)lds + (buf ^ 1) * 32768 + p * 8192 + wave * 2048;
        gload_lds16(pg[p] + kbyte + off[0], lw);
        gload_lds16(pg[p] + kbyte + off[1], lw + 1024);
      }
    }
#pragma unroll
    for (int i = 0; i < 4; ++i)
#pragma unroll
      for (int j = 0; j < 4; ++j) {
        S1[i][j] = __builtin_amdgcn_mfma_f32_16x16x32_f16(aH[i], bH[j], S1[i][j], 0, 0, 0);
        S2[i][j] = __builtin_amdgcn_mfma_f32_16x16x32_f16(aH[i], bL[j], S2[i][j], 0, 0, 0);
        S2[i][j] = __builtin_amdgcn_mfma_f32_16x16x32_f16(aL[i], bH[j], S2[i][j], 0, 0, 0);
      }
    __syncthreads();
    buf ^= 1;
  }

  // ---- fused epilogue: v = S1 + S2*2^-12; add bicubic taps; /3; max/argmax ----
  const float inv4096 = 1.0f / 4096.0f;
  const float* u2b = up2 + (size_t)b * 4096 * 1024;
  const float* u1b = up1 + (size_t)b * 4096 * 256;
#pragma unroll
  for (int j = 0; j < 4; ++j) {
    int gm = col0 + wx * 64 + j * 16 + lm;
    float src2 = (gm + 0.5f) * 0.25f - 0.5f;
    float f2 = floorf(src2); float t2 = src2 - f2; int i2 = (int)f2;
    int idx2[4]; float w2[4];
#pragma unroll
    for (int tp = 0; tp < 4; ++tp) {
      idx2[tp] = min(max(i2 + tp - 1, 0), 1023);
      w2[tp] = cubicw(t2 - (float)(tp - 1));
    }
    float src1 = (gm + 0.5f) * 0.0625f - 0.5f;
    float f1 = floorf(src1); float t1 = src1 - f1; int i1 = (int)f1;
    int idx1[4]; float w1[4];
#pragma unroll
    for (int tp = 0; tp < 4; ++tp) {
      idx1[tp] = min(max(i1 + tp - 1, 0), 255);
      w1[tp] = cubicw(t1 - (float)(tp - 1));
    }
    unsigned long long best = 0ull;
#pragma unroll
    for (int i = 0; i < 4; ++i) {
#pragma unroll
      for (int r = 0; r < 4; ++r) {
        int gn = row0 + wy * 64 + i * 16 + quad * 4 + r;
        float v = S1[i][j][r] + S2[i][j][r] * inv4096;
        const float* r2row = u2b + (size_t)gn * 1024;
        const float* r1row = u1b + (size_t)gn * 256;
        v += w2[0] * r2row[idx2[0]] + w2[1] * r2row[idx2[1]]
           + w2[2] * r2row[idx2[2]] + w2[3] * r2row[idx2[3]];
        v += w1[0] * r1row[idx1[0]] + w1[1] * r1row[idx1[1]]
           + w1[2] * r1row[idx1[2]] + w1[3] * r1row[idx1[3]];
        v *= (1.0f / 3.0f);
        unsigned int fb = __float_as_uint(v);
        unsigned int key = (fb & 0x80000000u) ? ~fb : (fb | 0x80000000u);
        unsigned long long pk = ((unsigned long long)key << 32)
                              | (unsigned long long)(0xFFFFFFFFu - (unsigned)gn);
        best = best > pk ? best : pk;
      }
    }
    // combine the 4 quads (same column gm, different row groups)
    unsigned long long o;
    o = __shfl_xor(best, 16); best = best > o ? best : o;
    o = __shfl_xor(best, 32); best = best > o ? best : o;
    if (lane < 16) atomicMax(&packed[(size_t)b * 4096 + gm], best);
  }
}

__global__ void finalize_kernel(const unsigned long long* __restrict__ packed,
                                float* __restrict__ s3_out, int* __restrict__ arg, int total) {
  int i = blockIdx.x * blockDim.x + threadIdx.x;
  if (i >= total) return;
  unsigned long long pk = packed[i];
  unsigned int key = (unsigned int)(pk >> 32);
  unsigned int fb = (key & 0x80000000u) ? (key ^ 0x80000000u) : ~key;
  s3_out[i] = __uint_as_float(fb);
  arg[i] = (int)(0xFFFFFFFFu - (unsigned int)(pk & 0xFFFFFFFFull));
}

// fold(gather(unfold(ref, KK,PP,SS), arg)) / 9 — pure gather, <=9 taps/output.
template<int KK, int SS, int PP>
__global__ void fold_gather_kernel(const float* __restrict__ ref, const int* __restrict__ arg,
                                   float* __restrict__ out, int C, int H, int W, int total) {
  int i = blockIdx.x * blockDim.x + threadIdx.x;
  if (i >= total) return;
  int w = i % W;
  int h = (i / W) % H;
  int c = (i / (W * H)) % C;
  int b = i / (W * H * C);
  int y = h + PP, x = w + PP;
  int ho_lo = (y - KK + 1) > 0 ? (y - KK + 1 + SS - 1) / SS : 0;
  int ho_hi = min(63, y / SS);
  int wo_lo = (x - KK + 1) > 0 ? (x - KK + 1 + SS - 1) / SS : 0;
  int wo_hi = min(63, x / SS);
  const int* argb = arg + b * 4096;
  const float* refb = ref + (size_t)(b * C + c) * H * W;
  float acc = 0.f;
  for (int ho = ho_lo; ho <= ho_hi; ++ho) {
    int ki = y - SS * ho;
    for (int wo = wo_lo; wo <= wo_hi; ++wo) {
      int kj = x - SS * wo;
      int q = argb[(ho << 6) + wo];
      int qh = q >> 6, qw = q & 63;
      int ry = SS * qh + ki - PP;
      int rx = SS * qw + kj - PP;
      if (ry >= 0 && ry < H && rx >= 0 && rx < W) acc += refb[ry * W + rx];
    }
  }
  out[i] = acc * (1.0f / 9.0f);
}

extern "C" void kernel_launch(void* const* d_in, const int* in_sizes, int n_in,
                              void* d_out, int out_size, void* d_ws, size_t ws_size,
                              hipStream_t stream) {
  const float* lrsr1 = (const float*)d_in[0];
  const float* lrsr2 = (const float*)d_in[1];
  const float* lrsr3 = (const float*)d_in[2];
  const float* refsr1 = (const float*)d_in[3];
  const float* refsr2 = (const float*)d_in[4];
  const float* refsr3 = (const float*)d_in[5];
  const float* ref1 = (const float*)d_in[6];
  const float* ref2 = (const float*)d_in[7];
  const float* ref3 = (const float*)d_in[8];
  float* out = (float*)d_out;
  float* ws = (float*)d_ws;

  const int B = 2;
  // level-3 f16 planes occupy the old r3n/l3n fp32 region exactly:
  // 4 planes x [2][4096][576] halves = 9,437,184 floats
  size_t off_planes = 0;
  size_t off_r2n = off_planes + (size_t)B * 4096 * 576 * 2; // floats (= 4 half-planes)
  size_t off_l2n = off_r2n + (size_t)B * 1024 * 1152;   // [2,1152,1024]
  size_t off_r1n = off_l2n + (size_t)B * 1152 * 1024;   // [2,256,2304]
  size_t off_l1n = off_r1n + (size_t)B * 256 * 2304;    // [2,2304,256]
  size_t off_R2  = off_l1n + (size_t)B * 2304 * 256;    // [2,1024,1024]
  size_t off_R1  = off_R2  + (size_t)B * 1024 * 1024;   // [2,256,256]
  size_t off_up2 = off_R1  + (size_t)B * 256 * 256;     // [2,4096,1024]
  size_t off_up1 = off_up2 + (size_t)B * 4096 * 1024;   // [2,4096,256]
  size_t off_S   = off_up1 + (size_t)B * 4096 * 256;    // [2,4096]
  size_t off_invn= off_S   + (size_t)B * 4096;          // [2,4096]
  size_t off_pk  = off_invn+ (size_t)B * 4096;          // [2,4096] u64
  size_t off_arg = off_pk  + (size_t)B * 4096 * 2;      // [2,4096] int

  const size_t PLANE = (size_t)B * 4096 * 576;          // halves per plane
  _Float16* r3hi = (_Float16*)(ws + off_planes);
  _Float16* r3lo = r3hi + PLANE;
  _Float16* l3hi = r3lo + PLANE;
  _Float16* l3lo = l3hi + PLANE;

  auto run_desc32 = [&](const float* x, int C, int H, int W, float* outbuf, bool r_layout) {
    int HW = H * W;
    int tS = B * HW;
    sumsq_kernel<<<DIVUP(tS, 256), 256, 0, stream>>>(x, ws + off_S, C, HW, tS);
    invnorm_kernel<<<DIVUP(tS, 256), 256, 0, stream>>>(ws + off_S, ws + off_invn, H, W, tS);
    int tD = B * C * 9 * HW;
    if (r_layout)
      desc_r_kernel<<<DIVUP(tD, 256), 256, 0, stream>>>(x, ws + off_invn, outbuf, C, H, W, tD);
    else
      desc_l_kernel<<<DIVUP(tD, 256), 256, 0, stream>>>(x, ws + off_invn, outbuf, C, H, W, tD);
  };
  auto run_desc_split = [&](const float* x, _Float16* hi, _Float16* lo) {
    int C = 64, H = 64, W = 64, HW = H * W;
    int tS = B * HW;
    sumsq_kernel<<<DIVUP(tS, 256), 256, 0, stream>>>(x, ws + off_S, C, HW, tS);
    invnorm_kernel<<<DIVUP(tS, 256), 256, 0, stream>>>(ws + off_S, ws + off_invn, H, W, tS);
    int tD = B * C * HW;
    desc_split_kernel<<<DIVUP(tD, 256), 256, 0, stream>>>(x, ws + off_invn, hi, lo, C, H, W, tD);
  };

  // level 3 split-f16 descriptors (both pixel-major [4096][576])
  run_desc_split(refsr3, r3hi, r3lo);
  run_desc_split(lrsr3, l3hi, l3lo);
  // levels 1/2 fp32 descriptors
  run_desc32(lrsr2, 128, 32, 32, ws + off_l2n, false);
  run_desc32(refsr2, 128, 32, 32, ws + off_r2n, true);
  run_desc32(lrsr1, 256, 16, 16, ws + off_l1n, false);
  run_desc32(refsr1, 256, 16, 16, ws + off_r1n, true);

  // small correlation GEMMs R2, R1 (fp32)
  {
    dim3 g(1024 / 64, 1024 / 64, B);
    gemm64_kernel<<<g, 256, 0, stream>>>(ws + off_r2n, ws + off_l2n, ws + off_R2,
                                         1024, 1024, 1152);
  }
  {
    dim3 g(256 / 64, 256 / 64, B);
    gemm64_kernel<<<g, 256, 0, stream>>>(ws + off_r1n, ws + off_l1n, ws + off_R1,
                                         256, 256, 2304);
  }

  // axis-1 bicubic upsample of R2 (x4) and R1 (x16) to 4096 rows
  {
    int tU2 = B * 4096 * 1024;
    upsample_n_kernel<<<DIVUP(tU2, 256), 256, 0, stream>>>(ws + off_R2, ws + off_up2,
                                                           1024, 1024, 0.25f, tU2);
    int tU1 = B * 4096 * 256;
    upsample_n_kernel<<<DIVUP(tU1, 256), 256, 0, stream>>>(ws + off_R1, ws + off_up1,
                                                           256, 256, 0.0625f, tU1);
  }

  unsigned long long* pk = (unsigned long long*)(ws + off_pk);
  init_packed_kernel<<<DIVUP(B * 4096, 256), 256, 0, stream>>>(pk, B * 4096);

  // fused R3 MFMA GEMM + bicubic add + max/argmax
  {
    dim3 g(4096 / 128, 4096 / 128, B);
    mfma_fused_kernel<<<g, 256, 0, stream>>>(r3hi, r3lo, l3hi, l3lo,
                                             ws + off_up2, ws + off_up1, pk);
  }

  int* argp = (int*)(ws + off_arg);
  finalize_kernel<<<DIVUP(B * 4096, 256), 256, 0, stream>>>(pk, out, argp, B * 4096);

  // transfer: fold(gather(unfold(ref_lvX)))/9
  float* T3 = out + 8192;
  float* T2 = T3 + (size_t)B * 256 * 64 * 64;
  float* T1 = T2 + (size_t)B * 128 * 128 * 128;
  {
    int tt = B * 256 * 64 * 64;
    fold_gather_kernel<3, 1, 1><<<DIVUP(tt, 256), 256, 0, stream>>>(ref3, argp, T3, 256, 64, 64, tt);
  }
  {
    int tt = B * 128 * 128 * 128;
    fold_gather_kernel<6, 2, 2><<<DIVUP(tt, 256), 256, 0, stream>>>(ref2, argp, T2, 128, 128, 128, tt);
  }
  {
    int tt = B * 64 * 256 * 256;
    fold_gather_kernel<12, 4, 4><<<DIVUP(tt, 256), 256, 0, stream>>>(ref1, argp, T1, 64, 256, 256, tt);
  }
}